// Round 15
// baseline (96.453 us; speedup 1.0000x reference)
//
#include <hip/hip_runtime.h>
#include <stdint.h>

// HamiltonianFlow: x [256, 8, 32, 2] (q,p); H = 0.5*sum(p^2) + MLP(q).
// dq/dt = p, dp/dt = -W u(z), z = W^T q + b1, u = (1-tanh^2(z)).*W2.
// z-space iteration with M = W^T W (R15-R23 verified).
//
// R37 = R35 VERBATIM (last green: 40.1us, bit-identical absmax) + ONLY
// the global-wBt epilogue. R36 bundled three changes (global wBt,
// exp2-fold, w4-factor) and FAILED (absmax 5.5e-2, non-reproducible
// across runs) with no way to attribute -> bisect conservatively.
// The global-wBt path is the one change that has run GREEN three times
// in exactly this form (R29c, R31, R32; absmax 0.001953125 each):
// wBt[kk][j] = W[c0][32kk+kq+j] = W1[c0*256+32kk+kq+j] -- contiguous
// float4 loads from L2-hot W1, same f32->f16 conversion as staging =>
// bit-identical values to R35's 64x conflicted ds_read_u16 column
// gather (wldsT[(32kk+kq+j)*WS+c0] is the same element). exp2-fold and
// w4-factor are DROPPED (one of them is R36's unexplained culprit).
//
// R35/R33 recap: COMBO-LINEARITY - advance/predictor need only
// A_j = Y1+Y2+Y3, B_j = Y1+2Y2+2Y3+Y4, Y_i = M u_i => sum u's BEFORE the
// matvec: row(2j) = uA_j = ua+ub+uc; row(2j+1) = uB_j = ua+2ub+2uc+ud.
// 16 rows = 8 steps/exchange, 12 full exchanges (H=8 measured optimum:
// 25ex->46.8, 13ex->40.5, 7ex->44.5). Tail steps 96-99 are S-ONLY
// (dead-code eliminated: its LDS/barrier/MFMA/advance outputs unread;
// S-adds consume per-lane pre-f16 u's directly).
// Exact 8-step advance: z += 8dt*P - dtdt6*SV8;  P -= dt6*SB8;
//   SB8 = sum B_j;  SV8 = sum (7-j)B_j + sum A_j
//   pred step j: Pp = P - (j/8)dt6*SBp;
//     zp2 = 2z + 2j*dt*P + dtdt6*j(8-j)/8*SBp - dtdt6*(j/4)*SVp
// Lane (quad q) owns steps j1=2q, j2=2q+1 (C rows 4q..4q+3 =
// {A_j1,B_j1,A_j2,B_j2} in-lane); V-partial = fma(7-j1, B1+B2, A1+A2-B2);
// 2 bfly4 per 8 steps. Stage-lags zc/zd use own-step A_prev/3 (KC folds).
// S-identities: sp = uB, sq = uA (pre-f16 f32); tail cn1 = 3-j1.
//
// R30 substrate: 16 waves x 1 tile (1024 thr), in-kernel W^T staging +
// M-build, ONE barrier per exchange (R24 double-buffer race argument),
// R30 bank-swizzle, permlane bfly4, exp-fold (2z chain) + rcp,
// mscr UNION ubuf (upool).
// FULL unroll on every reg-array access (R4: dynamic index => scratch).
// Numerics: f16 storage (W, M, uA/uB, S), fp32 MFMA accum + fp32 z/P.

typedef _Float16 v8h __attribute__((ext_vector_type(8)));
typedef float v4f __attribute__((ext_vector_type(4)));

#define NFULL 12  // full 8-step exchanges; steps 96-99 = eval-only tail
#define WS 264    // wldsT row stride (f16): row = one W-COLUMN, 16B-aligned
#define US 272    // ubuf row stride, f16 (544 B == 32 mod 128)

// D(+=C) in VGPRs, A (packed-vector frag) in VGPRs, B (M-frag) from AGPRs.
#define MFMA_AV(C, A, B) \
    asm("v_mfma_f32_16x16x32_f16 %0, %1, %2, %0" : "+v"(C) : "v"(A), "a"(B))

// 4-group butterfly sum over lanes {l, l^16, l^32, l^48}, pure VALU.
__device__ __forceinline__ float bfly4(float x) {
    float a = x, b = x;
    asm("v_permlane16_swap_b32 %0, %1" : "+v"(a), "+v"(b));
    float s = a + b;
    float c = s, d = s;
    asm("v_permlane32_swap_b32 %0, %1" : "+v"(c), "+v"(d));
    return c + d;
}

// u/(4*w2) eval on pre-doubled arg zz = 2*z:  r = rcp(e^zz + 1);
// u = 4*w2*(r - r^2)  ==  (1 - tanh^2(z)) * w2  exactly in algebra.
__device__ __forceinline__ float ueval2(float zz, float w4) {
    float e_ = __expf(zz);
    float r_ = __builtin_amdgcn_rcpf(e_ + 1.f);   // vs IEEE div: ~1e-7 rel
    return w4 * __builtin_fmaf(-r_, r_, r_);
}

__global__ __launch_bounds__(1024, 4)
void ham_kernel(const float* __restrict__ x0, const float* __restrict__ W1,
                const float* __restrict__ b1, const float* __restrict__ W2,
                float* __restrict__ out)
{
    __shared__ __align__(16)  _Float16 wldsT[256 * WS];  // 135168 B: W^T (f16)
    __shared__ __align__(128) char     upool[20480];     // mscr UNION ubuf
    float*    mscr = (float*)upool;                      // setup only
    _Float16* ubuf = (_Float16*)upool;                   // 2 x 16 rows x US

    const int t = threadIdx.x;
    const int w = t >> 6;          // wave 0..15: owns tile w (16 comps)
    const int l = t & 63;
    const int quad = l >> 4;       // owns steps 2*quad, 2*quad+1
    const int s = l & 15;          // owned column / A-row
    const int c0 = 16 * w + s;     // owned component
    const int blk = blockIdx.x;
    const int kq = 8 * quad;
    const int sel = (s & 3) * US;  // prologue/epilogue A-row select (rows 0-3)

    // ---- stage W^T -> LDS f16: wldsT[c][r] = W[r][c] ----
    {
        const int c = t & 255;
        const int rbase = (t >> 8) * 64;   // 4 quarters x 64 rows
        #pragma unroll 1
        for (int r0 = 0; r0 < 64; r0 += 8) {
            v8h h;
            #pragma unroll
            for (int j = 0; j < 8; ++j)
                h[j] = (_Float16)W1[(rbase + r0 + j) * 256 + c];
            *(v8h*)(wldsT + c * WS + rbase + r0) = h;   // b128, one-time
        }
    }
    __syncthreads();

    // ---- wF: own-column W^T frag (B-op), contiguous b128 from wldsT ----
    v8h wF0[8];
    #pragma unroll
    for (int kk = 0; kk < 8; ++kk)
        wF0[kk] = *(const v8h*)(wldsT + c0 * WS + 32 * kk + kq);

    // ---- build M = W^T W column-block frags wM0 (B-op: M[k][c0]) ----
    v8h wM0[8];
    float* scr0 = mscr + w * 320;
    #pragma unroll
    for (int kb = 0; kb < 16; ++kb) {
        v8h aM[8];   // A[m=s][k=8quad+j] = wldsT[(16kb+s)*WS + 32kk+kq+j]
        #pragma unroll
        for (int kk = 0; kk < 8; ++kk)
            aM[kk] = *(const v8h*)(wldsT + (16 * kb + s) * WS + 32 * kk + kq);
        v4f D0 = {0.f,0.f,0.f,0.f};
        #pragma unroll
        for (int kk = 0; kk < 8; ++kk)
            D0 = __builtin_amdgcn_mfma_f32_16x16x32_f16(aM[kk], wF0[kk], D0, 0, 0, 0);
        *(v4f*)(scr0 + s * 20 + 4 * quad) = D0;
        asm volatile("s_waitcnt lgkmcnt(0)" ::: "memory");  // in-wave x-lane
        if ((quad >> 1) == (kb & 1)) {
            #pragma unroll
            for (int j = 0; j < 8; ++j)
                wM0[kb >> 1][j] = (_Float16)scr0[s * 20 + 8 * (quad & 1) + j];
        }
        asm volatile("s_waitcnt lgkmcnt(0)" ::: "memory");
    }
    __syncthreads();   // mscr reads (all waves) done before ubuf reuse

    const float b1r0 = b1[c0];
    const float w4 = 4.f * W2[c0];
    float2 qp0 = ((const float2*)(x0 + (size_t)blk * 512))[c0];
    const float q0o0 = qp0.x, p0o0 = qp0.y;

    // ---- prologue: buf0 rows {q0, p0, 0, 0} -> z1 (C[0]), P (C[1]) ----
    if (quad == 0) {
        ubuf[c0] = (_Float16)q0o0;
        ubuf[US + c0] = (_Float16)p0o0;
        ubuf[2 * US + c0] = (_Float16)0.f;
        ubuf[3 * US + c0] = (_Float16)0.f;
    }
    __syncthreads();
    float z1, P;
    {
        const _Float16* ab = ubuf + sel + kq;
        v4f C0a = {0.f,0.f,0.f,0.f}, C0b = {0.f,0.f,0.f,0.f};
        #pragma unroll
        for (int kk = 0; kk < 8; kk += 2) {
            v8h a0 = *(const v8h*)(ab + 32 * kk);
            v8h a1 = *(const v8h*)(ab + 32 * (kk + 1));
            C0a = __builtin_amdgcn_mfma_f32_16x16x32_f16(a0, wF0[kk], C0a, 0, 0, 0);
            C0b = __builtin_amdgcn_mfma_f32_16x16x32_f16(a1, wF0[kk + 1], C0b, 0, 0, 0);
        }
        v4f C0s = C0a + C0b;
        z1 = C0s[0] + b1r0;  P = C0s[1];
    }
    __syncthreads();   // prologue reads done before u(0) overwrites buf0

    const float dt = 0.01f, hdt = 0.005f, dt6 = 0.01f / 6.f;
    const float dtdt6 = dt * dt6, hdt2 = hdt * hdt, dthdt = dt * hdt;
    const float K8dt = 8.f * dt;
    // steps j1 = 2q, j2 = 2q+1; horizon-8 predictor coefs (R29c-verified)
    const float j1 = 2.f * (float)quad, j2 = j1 + 1.f;
    const float cPn1 = -(j1 * 0.125f * dt6), cPn2 = -(j2 * 0.125f * dt6);
    const float Kz1a = 2.f * j1 * dt,        Kz1b = 2.f * j2 * dt;
    const float KB1 = dtdt6 * j1 * (8.f - j1) * 0.125f;
    const float KB2 = dtdt6 * j2 * (8.f - j2) * 0.125f;
    const float KVn1 = -(j1 * dtdt6 * 0.25f), KVn2 = -(j2 * dtdt6 * 0.25f);
    const float K2hdt = 2.f * hdt;
    const float K2dt  = 2.f * dt;
    const float KC1n = -(2.f * hdt2) / 3.f;   // zc: -2hdt^2 * (A/3) folded
    const float KC2n = -(2.f * dthdt) / 3.f;  // zd: -2*dt*hdt * (A/3) folded
    const float w71 = 7.f - j1;               // V = fma(w71, B1+B2, A1+A2-B2)

    // ---- ubuf addressing (R30 bank swizzle, kept) ----
    const int cw = c0 ^ (quad << 3);
    const int R0 = 4 * quad;
    const int wo0 = (R0 + 0) * US + cw;          // row 4q   = uA(j1)
    const int wo1 = (R0 + 1) * US + (cw ^ 32);   // row 4q+1 = uB(j1)
    const int wo2 = (R0 + 2) * US + cw;          // row 4q+2 = uA(j2)
    const int wo3 = (R0 + 3) * US + (cw ^ 32);   // row 4q+3 = uB(j2)
    const int sx = (s >> 2) & 3;
    const int rbase = s * US + 8 * (quad ^ sx);
    const int sodd = (s & 1) << 5;
    const _Float16* pe = ubuf + rbase + sodd;          // logical even kk
    const _Float16* po = ubuf + rbase + 32 - sodd;     // logical odd  kk

    // lag state (exchange 0: zeros -> benign one-time transient)
    float SBp = 0.f, SVp = 0.f;
    float AL1 = 0.f, AL2 = 0.f;    // own-step A-combo lags (Y1~Y2~A/3)
    float S1p = 0.f, S23p = 0.f;
    float cn1 = 99.f - j1;         // step n1 = 8e + j1; n2 = n1 + 1

    #pragma unroll 1
    for (int e = 0; e < NFULL; ++e) {
        const int bo = (e & 1) * (16 * US);   // double-buffer offset

        // ---- predict both steps; 8 stage-z's; 8 u evals; 4 combos ----
        float z1d = z1 + z1;
        float Pp1  = __builtin_fmaf(cPn1, SBp, P);
        float zp21 = __builtin_fmaf(Kz1a, P, z1d);
        zp21 = __builtin_fmaf(KB1, SBp, zp21);
        zp21 = __builtin_fmaf(KVn1, SVp, zp21);
        float zb21 = __builtin_fmaf(K2hdt, Pp1, zp21);
        float zc21 = __builtin_fmaf(KC1n, AL1, zb21);
        float zd21 = __builtin_fmaf(K2dt, Pp1, zp21);
        zd21 = __builtin_fmaf(KC2n, AL1, zd21);
        float Pp2  = __builtin_fmaf(cPn2, SBp, P);
        float zp22 = __builtin_fmaf(Kz1b, P, z1d);
        zp22 = __builtin_fmaf(KB2, SBp, zp22);
        zp22 = __builtin_fmaf(KVn2, SVp, zp22);
        float zb22 = __builtin_fmaf(K2hdt, Pp2, zp22);
        float zc22 = __builtin_fmaf(KC1n, AL2, zb22);
        float zd22 = __builtin_fmaf(K2dt, Pp2, zp22);
        zd22 = __builtin_fmaf(KC2n, AL2, zd22);

        float ua1 = ueval2(zp21, w4), ub1 = ueval2(zb21, w4);
        float uc1 = ueval2(zc21, w4), ud1 = ueval2(zd21, w4);
        float ua2 = ueval2(zp22, w4), ub2 = ueval2(zb22, w4);
        float uc2 = ueval2(zc22, w4), ud2 = ueval2(zd22, w4);

        float tv1 = ub1 + uc1;
        float uA1 = ua1 + tv1;                                // = sq(j1)
        float uB1 = __builtin_fmaf(2.f, tv1, ua1 + ud1);      // = sp(j1)
        float tv2 = ub2 + uc2;
        float uA2 = ua2 + tv2;
        float uB2 = __builtin_fmaf(2.f, tv2, ua2 + ud2);

        ubuf[bo + wo0] = (_Float16)uA1;
        ubuf[bo + wo1] = (_Float16)uB1;
        ubuf[bo + wo2] = (_Float16)uA2;
        ubuf[bo + wo3] = (_Float16)uB2;
        __syncthreads();   // the ONLY barrier per exchange (8 steps)

        // ---- ONE MFMA block: {A1,B1,A2,B2} combos for own comp ----
        v4f C0s;
        {
            v4f C0a = {0.f,0.f,0.f,0.f}, C0b = {0.f,0.f,0.f,0.f};
            #pragma unroll
            for (int kk = 0; kk < 8; kk += 2) {
                v8h a0 = *(const v8h*)(pe + bo + 32 * kk);
                v8h a1 = *(const v8h*)(po + bo + 32 * kk);
                MFMA_AV(C0a, a0, wM0[kk]);
                MFMA_AV(C0b, a1, wM0[kk + 1]);
            }
            C0s = C0a + C0b;
        }
        // no second barrier: next exchange writes the OTHER buffer (R24).

        // ---- EXACT 8-step advance via 2 butterflies ----
        float A1 = C0s[0], B1 = C0s[1], A2 = C0s[2], B2 = C0s[3];
        float Bs = B1 + B2;
        float V  = __builtin_fmaf(w71, Bs, A1 + A2 - B2);  // (7-j1)B1+(7-j2)B2+A1+A2
        float SB = bfly4(Bs);
        float SV = bfly4(V);

        z1 = __builtin_fmaf(K8dt, P, z1);      // z += 8dt*P (old P)
        z1 = __builtin_fmaf(-dtdt6, SV, z1);
        P  = __builtin_fmaf(-dt6, SB, P);

        SBp = SB;  SVp = SV;  AL1 = A1;  AL2 = A2;   // lag state

        // ---- S partials (identities sp=uB, sq=uA, pre-f16 f32) ----
        S1p += uB1 + uB2;
        S23p = __builtin_fmaf(cn1, uB1, S23p) + uA1;
        S23p = __builtin_fmaf(cn1 - 1.f, uB2, S23p) + uA2;
        cn1 -= 8.f;
    }

    // ---- tail, steps 96-99: S-ONLY (R35-verified dead-code elim) ----
    {
        const float vm = (quad < 2) ? 1.f : 0.f;
        float z1d = z1 + z1;
        float Pp1  = __builtin_fmaf(cPn1, SBp, P);
        float zp21 = __builtin_fmaf(Kz1a, P, z1d);
        zp21 = __builtin_fmaf(KB1, SBp, zp21);
        zp21 = __builtin_fmaf(KVn1, SVp, zp21);
        float zb21 = __builtin_fmaf(K2hdt, Pp1, zp21);
        float zc21 = __builtin_fmaf(KC1n, AL1, zb21);
        float zd21 = __builtin_fmaf(K2dt, Pp1, zp21);
        zd21 = __builtin_fmaf(KC2n, AL1, zd21);
        float Pp2  = __builtin_fmaf(cPn2, SBp, P);
        float zp22 = __builtin_fmaf(Kz1b, P, z1d);
        zp22 = __builtin_fmaf(KB2, SBp, zp22);
        zp22 = __builtin_fmaf(KVn2, SVp, zp22);
        float zb22 = __builtin_fmaf(K2hdt, Pp2, zp22);
        float zc22 = __builtin_fmaf(KC1n, AL2, zb22);
        float zd22 = __builtin_fmaf(K2dt, Pp2, zp22);
        zd22 = __builtin_fmaf(KC2n, AL2, zd22);

        float ua1 = ueval2(zp21, w4), ub1 = ueval2(zb21, w4);
        float uc1 = ueval2(zc21, w4), ud1 = ueval2(zd21, w4);
        float ua2 = ueval2(zp22, w4), ub2 = ueval2(zb22, w4);
        float uc2 = ueval2(zc22, w4), ud2 = ueval2(zd22, w4);

        float tv1 = ub1 + uc1;
        float uA1 = (ua1 + tv1) * vm;
        float uB1 = __builtin_fmaf(2.f, tv1, ua1 + ud1) * vm;
        float tv2 = ub2 + uc2;
        float uA2 = (ua2 + tv2) * vm;
        float uB2 = __builtin_fmaf(2.f, tv2, ua2 + ud2) * vm;

        S1p += uB1 + uB2;                       // cn1 = 3-j1 here (checked)
        S23p = __builtin_fmaf(cn1, uB1, S23p) + uA1;
        S23p = __builtin_fmaf(cn1 - 1.f, uB2, S23p) + uA2;
    }

    // ---- epilogue wBt from GLOBAL W1 (R29c/R31/R32-green path):
    //      wBt[kk][j] = W[c0][32kk+kq+j] = W1[c0*256+32kk+kq+j],
    //      contiguous float4, L2-hot, same f32->f16 conversion as
    //      staging => bit-identical to R35's conflicted LDS gather. ----
    v8h wBt0[8];
    #pragma unroll
    for (int kk = 0; kk < 8; ++kk) {
        const float* wp = W1 + c0 * 256 + 32 * kk + kq;
        v4f lo = *(const v4f*)(wp);
        v4f hi = *(const v4f*)(wp + 4);
        v8h h;
        h[0] = (_Float16)lo[0]; h[1] = (_Float16)lo[1];
        h[2] = (_Float16)lo[2]; h[3] = (_Float16)lo[3];
        h[4] = (_Float16)hi[0]; h[5] = (_Float16)hi[1];
        h[6] = (_Float16)hi[2]; h[7] = (_Float16)hi[3];
        wBt0[kk] = h;
    }

    // ---- epilogue: reduce S over quads; buf0 rows {S1, S23, 0, 0} ----
    const float S1f  = bfly4(S1p);
    const float S23f = bfly4(S23p);
    __syncthreads();   // all waves past loop (e=10 buf0-reads complete)
    if (quad == 0) {
        ubuf[c0] = (_Float16)S1f;
        ubuf[US + c0] = (_Float16)S23f;
        ubuf[2 * US + c0] = (_Float16)0.f;
        ubuf[3 * US + c0] = (_Float16)0.f;
    }
    __syncthreads();
    float D10, D20;
    {
        const _Float16* ab = ubuf + sel + kq;
        v4f C0a = {0.f,0.f,0.f,0.f}, C0b = {0.f,0.f,0.f,0.f};
        #pragma unroll
        for (int kk = 0; kk < 8; kk += 2) {
            v8h a0 = *(const v8h*)(ab + 32 * kk);
            v8h a1 = *(const v8h*)(ab + 32 * (kk + 1));
            C0a = __builtin_amdgcn_mfma_f32_16x16x32_f16(a0, wBt0[kk], C0a, 0, 0, 0);
            C0b = __builtin_amdgcn_mfma_f32_16x16x32_f16(a1, wBt0[kk + 1], C0b, 0, 0, 0);
        }
        v4f C0s = C0a + C0b;
        D10 = C0s[0];  D20 = C0s[1];
    }
    const float dt6e = 0.01f / 6.f, dtdt6e = 0.01f * dt6e;
    float pT0 = p0o0 - dt6e * D10;
    float qT0 = q0o0 + 0.01f * 100.f * p0o0 - dtdt6e * D20;

    if (quad == 0)
        ((float2*)(out + (size_t)blk * 512))[c0] = make_float2(qT0, pT0);
}

extern "C" void kernel_launch(void* const* d_in, const int* in_sizes, int n_in,
                              void* d_out, int out_size, void* d_ws, size_t ws_size,
                              hipStream_t stream) {
    const float* x0 = (const float*)d_in[0];
    const float* W1 = (const float*)d_in[1];
    const float* b1 = (const float*)d_in[2];
    const float* W2 = (const float*)d_in[3];
    // d_in[4] = b2: constant offset, no effect on the gradient/dynamics.
    float* out = (float*)d_out;
    hipLaunchKernelGGL(ham_kernel, dim3(256), dim3(1024), 0, stream,
                       x0, W1, b1, W2, out);
}

// Round 16
// 87.890 us; speedup vs baseline: 1.0974x; 1.0974x over previous
//
#include <hip/hip_runtime.h>
#include <stdint.h>

// HamiltonianFlow: x [256, 8, 32, 2] (q,p); H = 0.5*sum(p^2) + MLP(q).
// dq/dt = p, dp/dt = -W u(z), z = W^T q + b1, u = (1-tanh^2(z)).*W2.
// z-space iteration with M = W^T W (R15-R23 verified).
//
// R38 = R35 (best green: 40.1us, bit-identical absmax) + TAYLOR STAGE
// EVALS. R37 attributed: global-wBt numerically OK but a 4.4us REGRESSION
// (1024B-strided lane gather -> 64 cache lines/instr, 256-block L2 burst)
// -> epilogue reverted to R35's LDS gather. R36's culprit stays dropped.
// New (single) change: the 4 stage z's of a step differ from base zp by
// d <= 2dt|Pp| + O(dt^2 A) ~ 3e-3 z-units. Linearize around zp:
//   one eval: r = rcp(e^{2zp}+1), f = r-r^2, ua = w4*f, tanh = 1-2r,
//   du/d(2z) = -tanh*u  (exact derivative)
//   uA = ua+ub+uc = 3ua + u'*(db+dc);  uB = ua+2ub+2uc+ud
//      = 6ua + u'*(2(db+dc)+dd)
//   db = 2hdt*Pp; dc = db + KC1n*AL; dd = 2dt*Pp + KC2n*AL  [2z units]
// Taylor err = |u''| d^2/2 ~ 1e-6 absolute in uA -- >100x below uA's f16
// quantum (~1e-4) and 10x below the verified predictor-lag error class.
// Cuts 8 exp + 8 rcp -> 2 exp + 2 rcp and ~30 VALU/lane per exchange.
//
// R35/R33 recap: COMBO-LINEARITY - advance/predictor need only
// A_j = Y1+Y2+Y3, B_j = Y1+2Y2+2Y3+Y4, Y_i = M u_i => sum u's BEFORE the
// matvec: row(2j) = uA_j, row(2j+1) = uB_j. 16 rows = 8 steps/exchange,
// 12 full exchanges (H=8 measured optimum: 25ex->46.8, 13ex->40.5,
// 7ex->44.5). Tail steps 96-99 are S-ONLY (dead-code eliminated).
// Exact 8-step advance: z += 8dt*P - dtdt6*SV8;  P -= dt6*SB8;
//   SB8 = sum B_j;  SV8 = sum (7-j)B_j + sum A_j
//   pred step j: Pp = P - (j/8)dt6*SBp;
//     zp2 = 2z + 2j*dt*P + dtdt6*j(8-j)/8*SBp - dtdt6*(j/4)*SVp
// Lane (quad q) owns steps j1=2q, j2=2q+1 (C rows 4q..4q+3 =
// {A_j1,B_j1,A_j2,B_j2} in-lane); V-partial = fma(7-j1, B1+B2, A1+A2-B2);
// 2 bfly4 per 8 steps. Stage-lags use own-step A_prev/3 (KC folds).
// S-identities: sp = uB, sq = uA (pre-f16 f32); tail cn1 = 3-j1.
//
// R30 substrate: 16 waves x 1 tile (1024 thr), in-kernel W^T staging +
// M-build, ONE barrier per exchange (R24 double-buffer race argument),
// R30 bank-swizzle, permlane bfly4, mscr UNION ubuf (upool).
// FULL unroll on every reg-array access (R4: dynamic index => scratch).
// Numerics: f16 storage (W, M, uA/uB, S), fp32 MFMA accum + fp32 z/P.

typedef _Float16 v8h __attribute__((ext_vector_type(8)));
typedef float v4f __attribute__((ext_vector_type(4)));

#define NFULL 12  // full 8-step exchanges; steps 96-99 = eval-only tail
#define WS 264    // wldsT row stride (f16): row = one W-COLUMN, 16B-aligned
#define US 272    // ubuf row stride, f16 (544 B == 32 mod 128)

// D(+=C) in VGPRs, A (packed-vector frag) in VGPRs, B (M-frag) from AGPRs.
#define MFMA_AV(C, A, B) \
    asm("v_mfma_f32_16x16x32_f16 %0, %1, %2, %0" : "+v"(C) : "v"(A), "a"(B))

// 4-group butterfly sum over lanes {l, l^16, l^32, l^48}, pure VALU.
__device__ __forceinline__ float bfly4(float x) {
    float a = x, b = x;
    asm("v_permlane16_swap_b32 %0, %1" : "+v"(a), "+v"(b));
    float s = a + b;
    float c = s, d = s;
    asm("v_permlane32_swap_b32 %0, %1" : "+v"(c), "+v"(d));
    return c + d;
}

__global__ __launch_bounds__(1024, 4)
void ham_kernel(const float* __restrict__ x0, const float* __restrict__ W1,
                const float* __restrict__ b1, const float* __restrict__ W2,
                float* __restrict__ out)
{
    __shared__ __align__(16)  _Float16 wldsT[256 * WS];  // 135168 B: W^T (f16)
    __shared__ __align__(128) char     upool[20480];     // mscr UNION ubuf
    float*    mscr = (float*)upool;                      // setup only
    _Float16* ubuf = (_Float16*)upool;                   // 2 x 16 rows x US

    const int t = threadIdx.x;
    const int w = t >> 6;          // wave 0..15: owns tile w (16 comps)
    const int l = t & 63;
    const int quad = l >> 4;       // owns steps 2*quad, 2*quad+1
    const int s = l & 15;          // owned column / A-row
    const int c0 = 16 * w + s;     // owned component
    const int blk = blockIdx.x;
    const int kq = 8 * quad;
    const int sel = (s & 3) * US;  // prologue/epilogue A-row select (rows 0-3)

    // ---- stage W^T -> LDS f16: wldsT[c][r] = W[r][c] ----
    {
        const int c = t & 255;
        const int rbase = (t >> 8) * 64;   // 4 quarters x 64 rows
        #pragma unroll 1
        for (int r0 = 0; r0 < 64; r0 += 8) {
            v8h h;
            #pragma unroll
            for (int j = 0; j < 8; ++j)
                h[j] = (_Float16)W1[(rbase + r0 + j) * 256 + c];
            *(v8h*)(wldsT + c * WS + rbase + r0) = h;   // b128, one-time
        }
    }
    __syncthreads();

    // ---- wF: own-column W^T frag (B-op), contiguous b128 from wldsT ----
    v8h wF0[8];
    #pragma unroll
    for (int kk = 0; kk < 8; ++kk)
        wF0[kk] = *(const v8h*)(wldsT + c0 * WS + 32 * kk + kq);

    // ---- build M = W^T W column-block frags wM0 (B-op: M[k][c0]) ----
    v8h wM0[8];
    float* scr0 = mscr + w * 320;
    #pragma unroll
    for (int kb = 0; kb < 16; ++kb) {
        v8h aM[8];   // A[m=s][k=8quad+j] = wldsT[(16kb+s)*WS + 32kk+kq+j]
        #pragma unroll
        for (int kk = 0; kk < 8; ++kk)
            aM[kk] = *(const v8h*)(wldsT + (16 * kb + s) * WS + 32 * kk + kq);
        v4f D0 = {0.f,0.f,0.f,0.f};
        #pragma unroll
        for (int kk = 0; kk < 8; ++kk)
            D0 = __builtin_amdgcn_mfma_f32_16x16x32_f16(aM[kk], wF0[kk], D0, 0, 0, 0);
        *(v4f*)(scr0 + s * 20 + 4 * quad) = D0;
        asm volatile("s_waitcnt lgkmcnt(0)" ::: "memory");  // in-wave x-lane
        if ((quad >> 1) == (kb & 1)) {
            #pragma unroll
            for (int j = 0; j < 8; ++j)
                wM0[kb >> 1][j] = (_Float16)scr0[s * 20 + 8 * (quad & 1) + j];
        }
        asm volatile("s_waitcnt lgkmcnt(0)" ::: "memory");
    }
    __syncthreads();   // mscr reads (all waves) done before ubuf reuse

    const float b1r0 = b1[c0];
    const float w4 = 4.f * W2[c0];
    float2 qp0 = ((const float2*)(x0 + (size_t)blk * 512))[c0];
    const float q0o0 = qp0.x, p0o0 = qp0.y;

    // ---- prologue: buf0 rows {q0, p0, 0, 0} -> z1 (C[0]), P (C[1]) ----
    if (quad == 0) {
        ubuf[c0] = (_Float16)q0o0;
        ubuf[US + c0] = (_Float16)p0o0;
        ubuf[2 * US + c0] = (_Float16)0.f;
        ubuf[3 * US + c0] = (_Float16)0.f;
    }
    __syncthreads();
    float z1, P;
    {
        const _Float16* ab = ubuf + sel + kq;
        v4f C0a = {0.f,0.f,0.f,0.f}, C0b = {0.f,0.f,0.f,0.f};
        #pragma unroll
        for (int kk = 0; kk < 8; kk += 2) {
            v8h a0 = *(const v8h*)(ab + 32 * kk);
            v8h a1 = *(const v8h*)(ab + 32 * (kk + 1));
            C0a = __builtin_amdgcn_mfma_f32_16x16x32_f16(a0, wF0[kk], C0a, 0, 0, 0);
            C0b = __builtin_amdgcn_mfma_f32_16x16x32_f16(a1, wF0[kk + 1], C0b, 0, 0, 0);
        }
        v4f C0s = C0a + C0b;
        z1 = C0s[0] + b1r0;  P = C0s[1];
    }
    __syncthreads();   // prologue reads done before u(0) overwrites buf0

    const float dt = 0.01f, hdt = 0.005f, dt6 = 0.01f / 6.f;
    const float dtdt6 = dt * dt6, hdt2 = hdt * hdt, dthdt = dt * hdt;
    const float K8dt = 8.f * dt;
    // steps j1 = 2q, j2 = 2q+1; horizon-8 predictor coefs (R29c-verified)
    const float j1 = 2.f * (float)quad, j2 = j1 + 1.f;
    const float cPn1 = -(j1 * 0.125f * dt6), cPn2 = -(j2 * 0.125f * dt6);
    const float Kz1a = 2.f * j1 * dt,        Kz1b = 2.f * j2 * dt;
    const float KB1 = dtdt6 * j1 * (8.f - j1) * 0.125f;
    const float KB2 = dtdt6 * j2 * (8.f - j2) * 0.125f;
    const float KVn1 = -(j1 * dtdt6 * 0.25f), KVn2 = -(j2 * dtdt6 * 0.25f);
    const float K2hdt = 2.f * hdt;
    const float K2dt  = 2.f * dt;
    const float KC1n = -(2.f * hdt2) / 3.f;   // dc: -2hdt^2 * (A/3) folded
    const float KC2n = -(2.f * dthdt) / 3.f;  // dd: -2*dt*hdt * (A/3) folded
    const float w71 = 7.f - j1;               // V = fma(w71, B1+B2, A1+A2-B2)

    // ---- ubuf addressing (R30 bank swizzle, kept) ----
    const int cw = c0 ^ (quad << 3);
    const int R0 = 4 * quad;
    const int wo0 = (R0 + 0) * US + cw;          // row 4q   = uA(j1)
    const int wo1 = (R0 + 1) * US + (cw ^ 32);   // row 4q+1 = uB(j1)
    const int wo2 = (R0 + 2) * US + cw;          // row 4q+2 = uA(j2)
    const int wo3 = (R0 + 3) * US + (cw ^ 32);   // row 4q+3 = uB(j2)
    const int sx = (s >> 2) & 3;
    const int rbase = s * US + 8 * (quad ^ sx);
    const int sodd = (s & 1) << 5;
    const _Float16* pe = ubuf + rbase + sodd;          // logical even kk
    const _Float16* po = ubuf + rbase + 32 - sodd;     // logical odd  kk

    // lag state (exchange 0: zeros -> benign one-time transient)
    float SBp = 0.f, SVp = 0.f;
    float AL1 = 0.f, AL2 = 0.f;    // own-step A-combo lags (Y1~Y2~A/3)
    float S1p = 0.f, S23p = 0.f;
    float cn1 = 99.f - j1;         // step n1 = 8e + j1; n2 = n1 + 1

    #pragma unroll 1
    for (int e = 0; e < NFULL; ++e) {
        const int bo = (e & 1) * (16 * US);   // double-buffer offset

        // ---- predict both steps; ONE eval each; Taylor combos ----
        float z1d = z1 + z1;
        float Pp1  = __builtin_fmaf(cPn1, SBp, P);
        float zp21 = __builtin_fmaf(Kz1a, P, z1d);
        zp21 = __builtin_fmaf(KB1, SBp, zp21);
        zp21 = __builtin_fmaf(KVn1, SVp, zp21);
        float Pp2  = __builtin_fmaf(cPn2, SBp, P);
        float zp22 = __builtin_fmaf(Kz1b, P, z1d);
        zp22 = __builtin_fmaf(KB2, SBp, zp22);
        zp22 = __builtin_fmaf(KVn2, SVp, zp22);

        float e1 = __expf(zp21);
        float r1 = __builtin_amdgcn_rcpf(e1 + 1.f);
        float ua1 = w4 * __builtin_fmaf(-r1, r1, r1);       // w4*(r-r^2)
        float th1 = __builtin_fmaf(-2.f, r1, 1.f);          // tanh(z)
        float up1 = th1 * ua1;                              // -du/d(2z)
        float db1 = K2hdt * Pp1;
        float dc1 = __builtin_fmaf(KC1n, AL1, db1);
        float dd1 = __builtin_fmaf(K2dt, Pp1, KC2n * AL1);
        float sA1 = db1 + dc1;
        float sB1 = __builtin_fmaf(2.f, sA1, dd1);
        float u3a1 = 3.f * ua1;
        float uA1 = __builtin_fmaf(-up1, sA1, u3a1);        // 3ua + u'*sA
        float uB1 = __builtin_fmaf(-up1, sB1, u3a1 + u3a1); // 6ua + u'*sB

        float e2 = __expf(zp22);
        float r2 = __builtin_amdgcn_rcpf(e2 + 1.f);
        float ua2 = w4 * __builtin_fmaf(-r2, r2, r2);
        float th2 = __builtin_fmaf(-2.f, r2, 1.f);
        float up2 = th2 * ua2;
        float db2 = K2hdt * Pp2;
        float dc2 = __builtin_fmaf(KC1n, AL2, db2);
        float dd2 = __builtin_fmaf(K2dt, Pp2, KC2n * AL2);
        float sA2 = db2 + dc2;
        float sB2 = __builtin_fmaf(2.f, sA2, dd2);
        float u3a2 = 3.f * ua2;
        float uA2 = __builtin_fmaf(-up2, sA2, u3a2);
        float uB2 = __builtin_fmaf(-up2, sB2, u3a2 + u3a2);

        ubuf[bo + wo0] = (_Float16)uA1;
        ubuf[bo + wo1] = (_Float16)uB1;
        ubuf[bo + wo2] = (_Float16)uA2;
        ubuf[bo + wo3] = (_Float16)uB2;
        __syncthreads();   // the ONLY barrier per exchange (8 steps)

        // ---- ONE MFMA block: {A1,B1,A2,B2} combos for own comp ----
        v4f C0s;
        {
            v4f C0a = {0.f,0.f,0.f,0.f}, C0b = {0.f,0.f,0.f,0.f};
            #pragma unroll
            for (int kk = 0; kk < 8; kk += 2) {
                v8h a0 = *(const v8h*)(pe + bo + 32 * kk);
                v8h a1 = *(const v8h*)(po + bo + 32 * kk);
                MFMA_AV(C0a, a0, wM0[kk]);
                MFMA_AV(C0b, a1, wM0[kk + 1]);
            }
            C0s = C0a + C0b;
        }
        // no second barrier: next exchange writes the OTHER buffer (R24).

        // ---- EXACT 8-step advance via 2 butterflies ----
        float A1 = C0s[0], B1 = C0s[1], A2 = C0s[2], B2 = C0s[3];
        float Bs = B1 + B2;
        float V  = __builtin_fmaf(w71, Bs, A1 + A2 - B2);
        float SB = bfly4(Bs);
        float SV = bfly4(V);

        z1 = __builtin_fmaf(K8dt, P, z1);      // z += 8dt*P (old P)
        z1 = __builtin_fmaf(-dtdt6, SV, z1);
        P  = __builtin_fmaf(-dt6, SB, P);

        SBp = SB;  SVp = SV;  AL1 = A1;  AL2 = A2;   // lag state

        // ---- S partials (identities sp=uB, sq=uA, pre-f16 f32) ----
        S1p += uB1 + uB2;
        S23p = __builtin_fmaf(cn1, uB1, S23p) + uA1;
        S23p = __builtin_fmaf(cn1 - 1.f, uB2, S23p) + uA2;
        cn1 -= 8.f;
    }

    // ---- tail, steps 96-99: S-ONLY (R35-verified dead-code elim) ----
    {
        const float vm = (quad < 2) ? 1.f : 0.f;
        float z1d = z1 + z1;
        float Pp1  = __builtin_fmaf(cPn1, SBp, P);
        float zp21 = __builtin_fmaf(Kz1a, P, z1d);
        zp21 = __builtin_fmaf(KB1, SBp, zp21);
        zp21 = __builtin_fmaf(KVn1, SVp, zp21);
        float Pp2  = __builtin_fmaf(cPn2, SBp, P);
        float zp22 = __builtin_fmaf(Kz1b, P, z1d);
        zp22 = __builtin_fmaf(KB2, SBp, zp22);
        zp22 = __builtin_fmaf(KVn2, SVp, zp22);

        const float w4m = w4 * vm;
        float e1 = __expf(zp21);
        float r1 = __builtin_amdgcn_rcpf(e1 + 1.f);
        float ua1 = w4m * __builtin_fmaf(-r1, r1, r1);
        float th1 = __builtin_fmaf(-2.f, r1, 1.f);
        float up1 = th1 * ua1;
        float db1 = K2hdt * Pp1;
        float dc1 = __builtin_fmaf(KC1n, AL1, db1);
        float dd1 = __builtin_fmaf(K2dt, Pp1, KC2n * AL1);
        float sA1 = db1 + dc1;
        float sB1 = __builtin_fmaf(2.f, sA1, dd1);
        float u3a1 = 3.f * ua1;
        float uA1 = __builtin_fmaf(-up1, sA1, u3a1);
        float uB1 = __builtin_fmaf(-up1, sB1, u3a1 + u3a1);

        float e2 = __expf(zp22);
        float r2 = __builtin_amdgcn_rcpf(e2 + 1.f);
        float ua2 = w4m * __builtin_fmaf(-r2, r2, r2);
        float th2 = __builtin_fmaf(-2.f, r2, 1.f);
        float up2 = th2 * ua2;
        float db2 = K2hdt * Pp2;
        float dc2 = __builtin_fmaf(KC1n, AL2, db2);
        float dd2 = __builtin_fmaf(K2dt, Pp2, KC2n * AL2);
        float sA2 = db2 + dc2;
        float sB2 = __builtin_fmaf(2.f, sA2, dd2);
        float u3a2 = 3.f * ua2;
        float uA2 = __builtin_fmaf(-up2, sA2, u3a2);
        float uB2 = __builtin_fmaf(-up2, sB2, u3a2 + u3a2);

        S1p += uB1 + uB2;                       // cn1 = 3-j1 here (checked)
        S23p = __builtin_fmaf(cn1, uB1, S23p) + uA1;
        S23p = __builtin_fmaf(cn1 - 1.f, uB2, S23p) + uA2;
    }

    // ---- epilogue: reduce S over quads; buf0 rows {S1, S23, 0, 0} ----
    const float S1f  = bfly4(S1p);
    const float S23f = bfly4(S23p);
    __syncthreads();   // all waves past loop (e=10 buf0-reads complete)
    if (quad == 0) {
        ubuf[c0] = (_Float16)S1f;
        ubuf[US + c0] = (_Float16)S23f;
        ubuf[2 * US + c0] = (_Float16)0.f;
        ubuf[3 * US + c0] = (_Float16)0.f;
    }
    __syncthreads();
    // wBt[kk][j] = W[c0][32kk+kq+j] = wldsT[(32kk+kq+j)*WS + c0]
    // (LDS gather, R35 path: CU-local; global variant measured -4.4us, R37)
    v8h wBt0[8];
    #pragma unroll
    for (int kk = 0; kk < 8; ++kk)
        #pragma unroll
        for (int j = 0; j < 8; ++j)
            wBt0[kk][j] = wldsT[(32 * kk + kq + j) * WS + c0];
    float D10, D20;
    {
        const _Float16* ab = ubuf + sel + kq;
        v4f C0a = {0.f,0.f,0.f,0.f}, C0b = {0.f,0.f,0.f,0.f};
        #pragma unroll
        for (int kk = 0; kk < 8; kk += 2) {
            v8h a0 = *(const v8h*)(ab + 32 * kk);
            v8h a1 = *(const v8h*)(ab + 32 * (kk + 1));
            C0a = __builtin_amdgcn_mfma_f32_16x16x32_f16(a0, wBt0[kk], C0a, 0, 0, 0);
            C0b = __builtin_amdgcn_mfma_f32_16x16x32_f16(a1, wBt0[kk + 1], C0b, 0, 0, 0);
        }
        v4f C0s = C0a + C0b;
        D10 = C0s[0];  D20 = C0s[1];
    }
    const float dt6e = 0.01f / 6.f, dtdt6e = 0.01f * dt6e;
    float pT0 = p0o0 - dt6e * D10;
    float qT0 = q0o0 + 0.01f * 100.f * p0o0 - dtdt6e * D20;

    if (quad == 0)
        ((float2*)(out + (size_t)blk * 512))[c0] = make_float2(qT0, pT0);
}

extern "C" void kernel_launch(void* const* d_in, const int* in_sizes, int n_in,
                              void* d_out, int out_size, void* d_ws, size_t ws_size,
                              hipStream_t stream) {
    const float* x0 = (const float*)d_in[0];
    const float* W1 = (const float*)d_in[1];
    const float* b1 = (const float*)d_in[2];
    const float* W2 = (const float*)d_in[3];
    // d_in[4] = b2: constant offset, no effect on the gradient/dynamics.
    float* out = (float*)d_out;
    hipLaunchKernelGGL(ham_kernel, dim3(256), dim3(1024), 0, stream,
                       x0, W1, b1, W2, out);
}